// Round 1
// baseline (643.484 us; speedup 1.0000x reference)
//
#include <hip/hip_runtime.h>
#include <hip/hip_bf16.h>

#define N_DST1 50000
#define N_DST2 10000
#define FEAT   256

// ---------------- degree count ----------------
__global__ void count_deg_kernel(const int* __restrict__ dst, int E, int* __restrict__ deg) {
    int i = blockIdx.x * blockDim.x + threadIdx.x;
    if (i < E) atomicAdd(&deg[dst[i]], 1);
}

// ---------------- exclusive scan (single block, 1024 threads) ----------------
__global__ void excl_scan_kernel(const int* __restrict__ deg, int n,
                                 int* __restrict__ off, int* __restrict__ pos) {
    __shared__ int wsum[16];
    __shared__ int carry_s;
    int t = threadIdx.x;
    int lane = t & 63, wid = t >> 6;
    if (t == 0) carry_s = 0;
    __syncthreads();
    for (int base = 0; base < n; base += 1024) {
        int i = base + t;
        int v = (i < n) ? deg[i] : 0;
        int s = v;
        #pragma unroll
        for (int d = 1; d < 64; d <<= 1) {
            int u = __shfl_up(s, d, 64);
            if (lane >= d) s += u;
        }
        if (lane == 63) wsum[wid] = s;
        __syncthreads();
        if (wid == 0 && lane < 16) {
            int ws = wsum[lane];
            #pragma unroll
            for (int d = 1; d < 16; d <<= 1) {
                int u = __shfl_up(ws, d, 64);
                if (lane >= d) ws += u;
            }
            wsum[lane] = ws;  // inclusive scan of wave sums
        }
        __syncthreads();
        int waveoff = (wid == 0) ? 0 : wsum[wid - 1];
        int carry = carry_s;
        int excl = carry + waveoff + s - v;
        if (i < n) { off[i] = excl; pos[i] = excl; }
        __syncthreads();              // everyone read carry_s
        if (t == 0) carry_s = carry + wsum[15];
        __syncthreads();
    }
    if (t == 0) off[n] = carry_s;
}

// ---------------- scatter edges into CSR slots ----------------
__global__ void scatter_csr_kernel(const int* __restrict__ src, const int* __restrict__ dst,
                                   int E, int* __restrict__ pos, int* __restrict__ csr) {
    int i = blockIdx.x * blockDim.x + threadIdx.x;
    if (i < E) {
        int slot = atomicAdd(&pos[dst[i]], 1);
        csr[slot] = src[i];
    }
}

// ---------------- segment mean: one block (64 threads) per dst node ----------------
__global__ void seg_mean_kernel(const float* __restrict__ X, const int* __restrict__ off,
                                const int* __restrict__ csr, float* __restrict__ out) {
    int d = blockIdx.x;
    int t = threadIdx.x;          // 64 threads, each owns a float4 of the 256-dim row
    int beg = off[d], end = off[d + 1];
    float4 acc = make_float4(0.f, 0.f, 0.f, 0.f);
    for (int j = beg; j < end; ++j) {
        int s = csr[j];
        const float4 v = *reinterpret_cast<const float4*>(&X[(size_t)s * FEAT + t * 4]);
        acc.x += v.x; acc.y += v.y; acc.z += v.z; acc.w += v.w;
    }
    int degc = end - beg;
    float sc = 1.0f / (float)max(degc, 1);
    acc.x *= sc; acc.y *= sc; acc.z *= sc; acc.w *= sc;
    *reinterpret_cast<float4*>(&out[(size_t)d * FEAT + t * 4]) = acc;
}

// ---------------- tiled f32 GEMM on concat(A0, A1) @ W + b ----------------
// A row = [A0_row(256) | A1_row(256)], K = 512. Tile: 128 rows x (64*NCH) cols.
// 256 threads, each computes 8 rows x (4*NCH) cols.
template<int NCH, bool RELU>
__global__ __launch_bounds__(256) void gemm_cat_kernel(
    const float* __restrict__ A0, const float* __restrict__ A1,
    const float* __restrict__ W, const float* __restrict__ bias,
    float* __restrict__ C, int M, int Nfull)
{
    __shared__ float As[16][128];          // [k][row]
    __shared__ float Ws[16][64 * NCH];     // [k][col]
    const int t = threadIdx.x;
    const int tx = t & 15, ty = t >> 4;
    const int rowBase = blockIdx.y * 128;
    const int colBase = blockIdx.x * (64 * NCH);
    const int NT = 64 * NCH;

    float acc[2][NCH][16];
    #pragma unroll
    for (int rh = 0; rh < 2; ++rh)
        #pragma unroll
        for (int cc = 0; cc < NCH; ++cc)
            #pragma unroll
            for (int q = 0; q < 16; ++q) acc[rh][cc][q] = 0.f;

    for (int k0 = 0; k0 < 512; k0 += 16) {
        const float* Asrc = (k0 < 256) ? A0 : A1;
        const int kcol = k0 & 255;
        // stage A tile (128 rows x 16 k), transposed into LDS
        #pragma unroll
        for (int c = t; c < 512; c += 256) {
            int r = c >> 2, kq = (c & 3) * 4;
            int rg = rowBase + r;
            float4 v = make_float4(0.f, 0.f, 0.f, 0.f);
            if (rg < M) v = *reinterpret_cast<const float4*>(&Asrc[(size_t)rg * 256 + kcol + kq]);
            As[kq + 0][r] = v.x; As[kq + 1][r] = v.y;
            As[kq + 2][r] = v.z; As[kq + 3][r] = v.w;
        }
        // stage W tile (16 k x NT cols)
        #pragma unroll
        for (int c = t; c < 4 * NT; c += 256) {
            int NT4 = NT / 4;
            int k = c / NT4, cq = (c % NT4) * 4;
            float4 v = *reinterpret_cast<const float4*>(&W[(size_t)(k0 + k) * Nfull + colBase + cq]);
            *reinterpret_cast<float4*>(&Ws[k][cq]) = v;
        }
        __syncthreads();
        #pragma unroll 4
        for (int kk = 0; kk < 16; ++kk) {
            float4 a0 = *reinterpret_cast<const float4*>(&As[kk][ty * 4]);
            float4 a1 = *reinterpret_cast<const float4*>(&As[kk][ty * 4 + 64]);
            float av[2][4] = {{a0.x, a0.y, a0.z, a0.w}, {a1.x, a1.y, a1.z, a1.w}};
            #pragma unroll
            for (int cc = 0; cc < NCH; ++cc) {
                float4 w = *reinterpret_cast<const float4*>(&Ws[kk][tx * 4 + cc * 64]);
                float wv[4] = {w.x, w.y, w.z, w.w};
                #pragma unroll
                for (int rh = 0; rh < 2; ++rh)
                    #pragma unroll
                    for (int i = 0; i < 4; ++i)
                        #pragma unroll
                        for (int j = 0; j < 4; ++j)
                            acc[rh][cc][i * 4 + j] += av[rh][i] * wv[j];
            }
        }
        __syncthreads();
    }
    // epilogue
    #pragma unroll
    for (int rh = 0; rh < 2; ++rh)
        #pragma unroll
        for (int i = 0; i < 4; ++i) {
            int rg = rowBase + rh * 64 + ty * 4 + i;
            if (rg >= M) continue;
            #pragma unroll
            for (int cc = 0; cc < NCH; ++cc) {
                int cg = colBase + cc * 64 + tx * 4;
                float4 o;
                o.x = acc[rh][cc][i * 4 + 0] + bias[cg + 0];
                o.y = acc[rh][cc][i * 4 + 1] + bias[cg + 1];
                o.z = acc[rh][cc][i * 4 + 2] + bias[cg + 2];
                o.w = acc[rh][cc][i * 4 + 3] + bias[cg + 3];
                if (RELU) {
                    o.x = fmaxf(o.x, 0.f); o.y = fmaxf(o.y, 0.f);
                    o.z = fmaxf(o.z, 0.f); o.w = fmaxf(o.w, 0.f);
                }
                *reinterpret_cast<float4*>(&C[(size_t)rg * Nfull + cg]) = o;
            }
        }
}

extern "C" void kernel_launch(void* const* d_in, const int* in_sizes, int n_in,
                              void* d_out, int out_size, void* d_ws, size_t ws_size,
                              hipStream_t stream) {
    const float* x  = (const float*)d_in[0];
    const float* W1 = (const float*)d_in[1];
    const float* b1 = (const float*)d_in[2];
    const float* W2 = (const float*)d_in[3];
    const float* b2 = (const float*)d_in[4];
    const int* src1 = (const int*)d_in[5];
    const int* dst1 = (const int*)d_in[6];
    const int* src2 = (const int*)d_in[7];
    const int* dst2 = (const int*)d_in[8];
    const int E1 = in_sizes[5];
    const int E2 = in_sizes[7];
    float* out = (float*)d_out;

    // workspace carve-up (256B aligned)
    char* ws = (char*)d_ws;
    size_t o = 0;
    auto carve = [&](size_t bytes) { char* p = ws + o; o = (o + bytes + 255) & ~(size_t)255; return p; };
    int*   deg1 = (int*)  carve((size_t)N_DST1 * 4);
    int*   off1 = (int*)  carve((size_t)(N_DST1 + 1) * 4);
    int*   pos1 = (int*)  carve((size_t)N_DST1 * 4);
    int*   csr1 = (int*)  carve((size_t)E1 * 4);
    float* hN1  = (float*)carve((size_t)N_DST1 * FEAT * 4);
    float* h    = (float*)carve((size_t)N_DST1 * FEAT * 4);
    int*   deg2 = (int*)  carve((size_t)N_DST2 * 4);
    int*   off2 = (int*)  carve((size_t)(N_DST2 + 1) * 4);
    int*   pos2 = (int*)  carve((size_t)N_DST2 * 4);
    int*   csr2 = (int*)  carve((size_t)E2 * 4);
    float* hN2  = (float*)carve((size_t)N_DST2 * FEAT * 4);

    // ---- layer 1 ----
    hipMemsetAsync(deg1, 0, (size_t)N_DST1 * 4, stream);
    count_deg_kernel<<<(E1 + 255) / 256, 256, 0, stream>>>(dst1, E1, deg1);
    excl_scan_kernel<<<1, 1024, 0, stream>>>(deg1, N_DST1, off1, pos1);
    scatter_csr_kernel<<<(E1 + 255) / 256, 256, 0, stream>>>(src1, dst1, E1, pos1, csr1);
    seg_mean_kernel<<<N_DST1, 64, 0, stream>>>(x, off1, csr1, hN1);
    // h = relu(concat(x[:N_DST1], hN1) @ W1 + b1)
    gemm_cat_kernel<2, true><<<dim3(2, (N_DST1 + 127) / 128), 256, 0, stream>>>(
        x, hN1, W1, b1, h, N_DST1, 256);

    // ---- layer 2 ----
    hipMemsetAsync(deg2, 0, (size_t)N_DST2 * 4, stream);
    count_deg_kernel<<<(E2 + 255) / 256, 256, 0, stream>>>(dst2, E2, deg2);
    excl_scan_kernel<<<1, 1024, 0, stream>>>(deg2, N_DST2, off2, pos2);
    scatter_csr_kernel<<<(E2 + 255) / 256, 256, 0, stream>>>(src2, dst2, E2, pos2, csr2);
    seg_mean_kernel<<<N_DST2, 64, 0, stream>>>(h, off2, csr2, hN2);
    // out = concat(h[:N_DST2], hN2) @ W2 + b2
    gemm_cat_kernel<1, false><<<dim3(1, (N_DST2 + 127) / 128), 256, 0, stream>>>(
        h, hN2, W2, b2, out, N_DST2, 64);
}

// Round 2
// 445.216 us; speedup vs baseline: 1.4453x; 1.4453x over previous
//
#include <hip/hip_runtime.h>
#include <hip/hip_bf16.h>

#define N_DST1 50000
#define N_DST2 10000
#define FEAT   256

typedef unsigned int u32;
typedef __attribute__((ext_vector_type(4))) float f32x4;
typedef __attribute__((ext_vector_type(8))) short bf16x8;

__device__ __forceinline__ ushort f2bf(float f) {
    u32 u = __float_as_uint(f);
    u32 r = (u + 0x7FFFu + ((u >> 16) & 1u)) >> 16;
    return (ushort)r;
}
__device__ __forceinline__ float bf2f(ushort u) {
    return __uint_as_float(((u32)u) << 16);
}

__device__ __forceinline__ void gload_lds16(const void* g, void* l) {
    __builtin_amdgcn_global_load_lds(
        (const __attribute__((address_space(1))) u32*)g,
        (__attribute__((address_space(3))) u32*)l, 16, 0, 0);
}

// ---------------- degree count ----------------
__global__ void count_deg_kernel(const int* __restrict__ dst, int E, int* __restrict__ deg) {
    int i = blockIdx.x * blockDim.x + threadIdx.x;
    if (i < E) atomicAdd(&deg[dst[i]], 1);
}

// ---------------- exclusive scan (single block, 1024 threads) ----------------
__global__ void excl_scan_kernel(const int* __restrict__ deg, int n,
                                 int* __restrict__ off, int* __restrict__ pos) {
    __shared__ int wsum[16];
    __shared__ int carry_s;
    int t = threadIdx.x;
    int lane = t & 63, wid = t >> 6;
    if (t == 0) carry_s = 0;
    __syncthreads();
    for (int base = 0; base < n; base += 1024) {
        int i = base + t;
        int v = (i < n) ? deg[i] : 0;
        int s = v;
        #pragma unroll
        for (int d = 1; d < 64; d <<= 1) {
            int u = __shfl_up(s, d, 64);
            if (lane >= d) s += u;
        }
        if (lane == 63) wsum[wid] = s;
        __syncthreads();
        if (wid == 0 && lane < 16) {
            int ws = wsum[lane];
            #pragma unroll
            for (int d = 1; d < 16; d <<= 1) {
                int u = __shfl_up(ws, d, 64);
                if (lane >= d) ws += u;
            }
            wsum[lane] = ws;
        }
        __syncthreads();
        int waveoff = (wid == 0) ? 0 : wsum[wid - 1];
        int carry = carry_s;
        int excl = carry + waveoff + s - v;
        if (i < n) { off[i] = excl; pos[i] = excl; }
        __syncthreads();
        if (t == 0) carry_s = carry + wsum[15];
        __syncthreads();
    }
    if (t == 0) off[n] = carry_s;
}

// ---------------- scatter edges into CSR slots ----------------
__global__ void scatter_csr_kernel(const int* __restrict__ src, const int* __restrict__ dst,
                                   int E, int* __restrict__ pos, int* __restrict__ csr) {
    int i = blockIdx.x * blockDim.x + threadIdx.x;
    if (i < E) {
        int slot = atomicAdd(&pos[dst[i]], 1);
        csr[slot] = src[i];
    }
}

// ---------------- f32 -> bf16 conversion (8 elems/thread) ----------------
__global__ void cvt_bf16_kernel(const float* __restrict__ in, ushort* __restrict__ out, int n8) {
    int i = blockIdx.x * blockDim.x + threadIdx.x;
    if (i >= n8) return;
    const float4* p = (const float4*)in + (size_t)i * 2;
    float4 a = p[0], b = p[1];
    ushort4 lo = make_ushort4(f2bf(a.x), f2bf(a.y), f2bf(a.z), f2bf(a.w));
    ushort4 hi = make_ushort4(f2bf(b.x), f2bf(b.y), f2bf(b.z), f2bf(b.w));
    ushort4* q = (ushort4*)out + (size_t)i * 2;
    q[0] = lo; q[1] = hi;
}

// ---------------- W [512][N] f32 -> WT [N][512] bf16 ----------------
__global__ void cvt_wt_kernel(const float* __restrict__ W, ushort* __restrict__ WT, int N) {
    int k = blockIdx.x;          // 512 blocks
    int n = threadIdx.x;         // N threads
    WT[(size_t)n * 512 + k] = f2bf(W[(size_t)k * N + n]);
}

// ---------------- segment mean: one wave per dst node ----------------
// BF16IN: gather bf16 rows; else f32 rows. Output bf16 [d][256].
template<bool BF16IN>
__global__ void seg_mean_kernel(const void* __restrict__ Xv, const int* __restrict__ off,
                                const int* __restrict__ csr, ushort* __restrict__ out) {
    int d = blockIdx.x;
    int t = threadIdx.x;          // 64 threads, each owns 4 of the 256 features
    int beg = off[d], end = off[d + 1];
    float a0 = 0.f, a1 = 0.f, a2 = 0.f, a3 = 0.f;
    if (BF16IN) {
        const ushort* X = (const ushort*)Xv;
        for (int j = beg; j < end; ++j) {
            int s = csr[j];
            ushort4 v = *reinterpret_cast<const ushort4*>(&X[(size_t)s * FEAT + t * 4]);
            a0 += bf2f(v.x); a1 += bf2f(v.y); a2 += bf2f(v.z); a3 += bf2f(v.w);
        }
    } else {
        const float* X = (const float*)Xv;
        for (int j = beg; j < end; ++j) {
            int s = csr[j];
            float4 v = *reinterpret_cast<const float4*>(&X[(size_t)s * FEAT + t * 4]);
            a0 += v.x; a1 += v.y; a2 += v.z; a3 += v.w;
        }
    }
    float sc = 1.0f / (float)max(end - beg, 1);
    ushort4 o = make_ushort4(f2bf(a0 * sc), f2bf(a1 * sc), f2bf(a2 * sc), f2bf(a3 * sc));
    *reinterpret_cast<ushort4*>(&out[(size_t)d * FEAT + t * 4]) = o;
}

// ---------------- bf16 MFMA GEMM: C = concat(A0,A1) @ BT^T + bias ----------------
// A0,A1: [M][256] bf16 (K halves). BT: [N][512] bf16 (W transposed). K=512.
// Tile BM x BN, WGM x WGN waves, each wave computes (BM/WGM) x (BN/WGN).
template<int BM, int BN, int WGM, int WGN, bool RELU, bool OBF16>
__global__ __launch_bounds__(WGM * WGN * 64)
void gemm_mfma_kernel(const ushort* __restrict__ A0, const ushort* __restrict__ A1,
                      const ushort* __restrict__ BT, const float* __restrict__ bias,
                      ushort* __restrict__ Cb, float* __restrict__ Cf,
                      int M, int Nfull) {
    constexpr int NWAVE = WGM * WGN;
    constexpr int WM = BM / WGM;          // rows per wave
    constexpr int WN = BN / WGN;          // cols per wave
    constexpr int MF = WM / 16;           // 16x16 frags in M
    constexpr int NF = WN / 16;
    constexpr int ACH = BM / 16;          // 1024B staging chunks for A tile
    constexpr int BCH = BN / 16;

    __shared__ ushort Al[2][BM][32];
    __shared__ ushort Bl[2][BN][32];

    const int t = threadIdx.x;
    const int lane = t & 63;
    const int wid = t >> 6;
    const int wm = wid / WGN, wn = wid % WGN;
    const int lr = lane & 15, grp = lane >> 4;
    const int rowBase = blockIdx.y * BM;
    const int colBase = blockIdx.x * BN;

    f32x4 acc[MF][NF];
    #pragma unroll
    for (int m = 0; m < MF; ++m)
        #pragma unroll
        for (int n = 0; n < NF; ++n)
            acc[m][n] = (f32x4){0.f, 0.f, 0.f, 0.f};

    // staging lambda: kt in [0,16)
    auto stage = [&](int buf, int kt) {
        const ushort* Asrc = (kt < 8) ? A0 : A1;
        const int kcol = (kt * 32) & 255;
        #pragma unroll
        for (int ch = wid; ch < ACH; ch += NWAVE) {
            int r = ch * 16 + (lane >> 2);
            int rg = min(rowBase + r, M - 1);
            int c = lane & 3;
            int ksw = (c ^ (r & 3)) * 8;
            gload_lds16(&Asrc[(size_t)rg * 256 + kcol + ksw], &Al[buf][ch * 16][0]);
        }
        #pragma unroll
        for (int ch = wid; ch < BCH; ch += NWAVE) {
            int r = ch * 16 + (lane >> 2);
            int c = lane & 3;
            int ksw = (c ^ (r & 3)) * 8;
            gload_lds16(&BT[(size_t)(colBase + r) * 512 + kt * 32 + ksw], &Bl[buf][ch * 16][0]);
        }
    };

    stage(0, 0);
    __syncthreads();

    int buf = 0;
    for (int kt = 0; kt < 16; ++kt) {
        if (kt + 1 < 16) stage(buf ^ 1, kt + 1);
        bf16x8 af[MF], bfr[NF];
        #pragma unroll
        for (int m = 0; m < MF; ++m) {
            int r = wm * WM + m * 16 + lr;
            af[m] = *reinterpret_cast<const bf16x8*>(
                (const char*)&Al[buf][0][0] + r * 64 + ((grp ^ (r & 3)) << 4));
        }
        #pragma unroll
        for (int n = 0; n < NF; ++n) {
            int r = wn * WN + n * 16 + lr;
            bfr[n] = *reinterpret_cast<const bf16x8*>(
                (const char*)&Bl[buf][0][0] + r * 64 + ((grp ^ (r & 3)) << 4));
        }
        #pragma unroll
        for (int m = 0; m < MF; ++m)
            #pragma unroll
            for (int n = 0; n < NF; ++n)
                acc[m][n] = __builtin_amdgcn_mfma_f32_16x16x32_bf16(af[m], bfr[n], acc[m][n], 0, 0, 0);
        __syncthreads();
        buf ^= 1;
    }

    // epilogue
    #pragma unroll
    for (int m = 0; m < MF; ++m) {
        #pragma unroll
        for (int q = 0; q < 4; ++q) {
            int rowg = rowBase + wm * WM + m * 16 + grp * 4 + q;
            if (rowg >= M) continue;
            #pragma unroll
            for (int n = 0; n < NF; ++n) {
                int colg = colBase + wn * WN + n * 16 + lr;
                float v = acc[m][n][q] + bias[colg];
                if (RELU) v = fmaxf(v, 0.f);
                if (OBF16) Cb[(size_t)rowg * Nfull + colg] = f2bf(v);
                else       Cf[(size_t)rowg * Nfull + colg] = v;
            }
        }
    }
}

extern "C" void kernel_launch(void* const* d_in, const int* in_sizes, int n_in,
                              void* d_out, int out_size, void* d_ws, size_t ws_size,
                              hipStream_t stream) {
    const float* x  = (const float*)d_in[0];
    const float* W1 = (const float*)d_in[1];
    const float* b1 = (const float*)d_in[2];
    const float* W2 = (const float*)d_in[3];
    const float* b2 = (const float*)d_in[4];
    const int* src1 = (const int*)d_in[5];
    const int* dst1 = (const int*)d_in[6];
    const int* src2 = (const int*)d_in[7];
    const int* dst2 = (const int*)d_in[8];
    const int E1 = in_sizes[5];
    const int E2 = in_sizes[7];
    float* out = (float*)d_out;

    char* ws = (char*)d_ws;
    size_t o = 0;
    auto carve = [&](size_t bytes) { char* p = ws + o; o = (o + bytes + 255) & ~(size_t)255; return p; };
    int*    deg1 = (int*)   carve((size_t)N_DST1 * 4);
    int*    off1 = (int*)   carve((size_t)(N_DST1 + 1) * 4);
    int*    pos1 = (int*)   carve((size_t)N_DST1 * 4);
    int*    csr1 = (int*)   carve((size_t)E1 * 4);
    ushort* xb   = (ushort*)carve((size_t)N_DST1 * FEAT * 2);   // bf16 of x[:50000]
    ushort* hN1b = (ushort*)carve((size_t)N_DST1 * FEAT * 2);
    ushort* hb   = (ushort*)carve((size_t)N_DST1 * FEAT * 2);   // layer-1 output (bf16)
    int*    deg2 = (int*)   carve((size_t)N_DST2 * 4);
    int*    off2 = (int*)   carve((size_t)(N_DST2 + 1) * 4);
    int*    pos2 = (int*)   carve((size_t)N_DST2 * 4);
    int*    csr2 = (int*)   carve((size_t)E2 * 4);
    ushort* hN2b = (ushort*)carve((size_t)N_DST2 * FEAT * 2);
    ushort* W1T  = (ushort*)carve((size_t)256 * 512 * 2);
    ushort* W2T  = (ushort*)carve((size_t)64 * 512 * 2);

    // ---- CSR build, layer 1 ----
    hipMemsetAsync(deg1, 0, (size_t)N_DST1 * 4, stream);
    count_deg_kernel<<<(E1 + 255) / 256, 256, 0, stream>>>(dst1, E1, deg1);
    excl_scan_kernel<<<1, 1024, 0, stream>>>(deg1, N_DST1, off1, pos1);
    scatter_csr_kernel<<<(E1 + 255) / 256, 256, 0, stream>>>(src1, dst1, E1, pos1, csr1);

    // ---- conversions ----
    cvt_bf16_kernel<<<((N_DST1 * FEAT / 8) + 255) / 256, 256, 0, stream>>>(x, xb, N_DST1 * FEAT / 8);
    cvt_wt_kernel<<<512, 256, 0, stream>>>(W1, W1T, 256);
    cvt_wt_kernel<<<512, 64, 0, stream>>>(W2, W2T, 64);

    // ---- layer 1 aggregate (f32 gather, bf16 out) + GEMM ----
    seg_mean_kernel<false><<<N_DST1, 64, 0, stream>>>(x, off1, csr1, hN1b);
    gemm_mfma_kernel<128, 128, 2, 2, true, true><<<dim3(256 / 128, (N_DST1 + 127) / 128), 256, 0, stream>>>(
        xb, hN1b, W1T, b1, hb, nullptr, N_DST1, 256);

    // ---- CSR build, layer 2 ----
    hipMemsetAsync(deg2, 0, (size_t)N_DST2 * 4, stream);
    count_deg_kernel<<<(E2 + 255) / 256, 256, 0, stream>>>(dst2, E2, deg2);
    excl_scan_kernel<<<1, 1024, 0, stream>>>(deg2, N_DST2, off2, pos2);
    scatter_csr_kernel<<<(E2 + 255) / 256, 256, 0, stream>>>(src2, dst2, E2, pos2, csr2);

    // ---- layer 2 aggregate (bf16 gather) + GEMM (f32 out) ----
    seg_mean_kernel<true><<<N_DST2, 64, 0, stream>>>(hb, off2, csr2, hN2b);
    gemm_mfma_kernel<128, 64, 2, 2, false, false><<<dim3(64 / 64, (N_DST2 + 127) / 128), 256, 0, stream>>>(
        hb, hN2b, W2T, b2, nullptr, out, N_DST2, 64);
}

// Round 3
// 403.077 us; speedup vs baseline: 1.5964x; 1.1045x over previous
//
#include <hip/hip_runtime.h>
#include <hip/hip_bf16.h>

#define N_DST1 50000
#define N_DST2 10000
#define FEAT   256

typedef unsigned int u32;
typedef __attribute__((ext_vector_type(4))) float f32x4;
typedef __attribute__((ext_vector_type(8))) short bf16x8;

__device__ __forceinline__ ushort f2bf(float f) {
    u32 u = __float_as_uint(f);
    u32 r = (u + 0x7FFFu + ((u >> 16) & 1u)) >> 16;
    return (ushort)r;
}
__device__ __forceinline__ float bf2f(ushort u) {
    return __uint_as_float(((u32)u) << 16);
}

__device__ __forceinline__ void gload_lds16(const void* g, void* l) {
    __builtin_amdgcn_global_load_lds(
        (const __attribute__((address_space(1))) u32*)g,
        (__attribute__((address_space(3))) u32*)l, 16, 0, 0);
}

// ---------------- degree count ----------------
__global__ void count_deg_kernel(const int* __restrict__ dst, int E, int* __restrict__ deg) {
    int i = blockIdx.x * blockDim.x + threadIdx.x;
    if (i < E) atomicAdd(&deg[dst[i]], 1);
}

// ---------------- exclusive scan (single block, 1024 threads) ----------------
__global__ void excl_scan_kernel(const int* __restrict__ deg, int n,
                                 int* __restrict__ off, int* __restrict__ pos) {
    __shared__ int wsum[16];
    __shared__ int carry_s;
    int t = threadIdx.x;
    int lane = t & 63, wid = t >> 6;
    if (t == 0) carry_s = 0;
    __syncthreads();
    for (int base = 0; base < n; base += 1024) {
        int i = base + t;
        int v = (i < n) ? deg[i] : 0;
        int s = v;
        #pragma unroll
        for (int d = 1; d < 64; d <<= 1) {
            int u = __shfl_up(s, d, 64);
            if (lane >= d) s += u;
        }
        if (lane == 63) wsum[wid] = s;
        __syncthreads();
        if (wid == 0 && lane < 16) {
            int ws = wsum[lane];
            #pragma unroll
            for (int d = 1; d < 16; d <<= 1) {
                int u = __shfl_up(ws, d, 64);
                if (lane >= d) ws += u;
            }
            wsum[lane] = ws;
        }
        __syncthreads();
        int waveoff = (wid == 0) ? 0 : wsum[wid - 1];
        int carry = carry_s;
        int excl = carry + waveoff + s - v;
        if (i < n) { off[i] = excl; pos[i] = excl; }
        __syncthreads();
        if (t == 0) carry_s = carry + wsum[15];
        __syncthreads();
    }
    if (t == 0) off[n] = carry_s;
}

// ---------------- scatter edges into CSR slots ----------------
__global__ void scatter_csr_kernel(const int* __restrict__ src, const int* __restrict__ dst,
                                   int E, int* __restrict__ pos, int* __restrict__ csr) {
    int i = blockIdx.x * blockDim.x + threadIdx.x;
    if (i < E) {
        int slot = atomicAdd(&pos[dst[i]], 1);
        csr[slot] = src[i];
    }
}

// ---------------- f32 -> bf16 conversion (8 elems/thread) ----------------
__global__ void cvt_bf16_kernel(const float* __restrict__ in, ushort* __restrict__ out, int n8) {
    int i = blockIdx.x * blockDim.x + threadIdx.x;
    if (i >= n8) return;
    const float4* p = (const float4*)in + (size_t)i * 2;
    float4 a = p[0], b = p[1];
    ushort4 lo = make_ushort4(f2bf(a.x), f2bf(a.y), f2bf(a.z), f2bf(a.w));
    ushort4 hi = make_ushort4(f2bf(b.x), f2bf(b.y), f2bf(b.z), f2bf(b.w));
    ushort4* q = (ushort4*)out + (size_t)i * 2;
    q[0] = lo; q[1] = hi;
}

// ---------------- W [512][N] f32 -> WT [N][512] bf16 ----------------
__global__ void cvt_wt_kernel(const float* __restrict__ W, ushort* __restrict__ WT, int N) {
    int k = blockIdx.x;          // 512 blocks
    int n = threadIdx.x;         // N threads
    WT[(size_t)n * 512 + k] = f2bf(W[(size_t)k * N + n]);
}

// ---------------- segment mean (bf16 gather), 4x unrolled for MLP ----------------
__global__ void seg_mean_bf16_kernel(const ushort* __restrict__ X, const int* __restrict__ off,
                                     const int* __restrict__ csr, ushort* __restrict__ out) {
    int d = blockIdx.x;
    int t = threadIdx.x;          // 64 threads, each owns 4 of the 256 features
    int beg = off[d], end = off[d + 1];
    float a0 = 0.f, a1 = 0.f, a2 = 0.f, a3 = 0.f;
    int j = beg;
    for (; j + 4 <= end; j += 4) {
        int s0 = csr[j], s1 = csr[j + 1], s2 = csr[j + 2], s3 = csr[j + 3];
        ushort4 v0 = *reinterpret_cast<const ushort4*>(&X[(size_t)s0 * FEAT + t * 4]);
        ushort4 v1 = *reinterpret_cast<const ushort4*>(&X[(size_t)s1 * FEAT + t * 4]);
        ushort4 v2 = *reinterpret_cast<const ushort4*>(&X[(size_t)s2 * FEAT + t * 4]);
        ushort4 v3 = *reinterpret_cast<const ushort4*>(&X[(size_t)s3 * FEAT + t * 4]);
        a0 += bf2f(v0.x) + bf2f(v1.x) + bf2f(v2.x) + bf2f(v3.x);
        a1 += bf2f(v0.y) + bf2f(v1.y) + bf2f(v2.y) + bf2f(v3.y);
        a2 += bf2f(v0.z) + bf2f(v1.z) + bf2f(v2.z) + bf2f(v3.z);
        a3 += bf2f(v0.w) + bf2f(v1.w) + bf2f(v2.w) + bf2f(v3.w);
    }
    for (; j < end; ++j) {
        int s = csr[j];
        ushort4 v = *reinterpret_cast<const ushort4*>(&X[(size_t)s * FEAT + t * 4]);
        a0 += bf2f(v.x); a1 += bf2f(v.y); a2 += bf2f(v.z); a3 += bf2f(v.w);
    }
    float sc = 1.0f / (float)max(end - beg, 1);
    ushort4 o = make_ushort4(f2bf(a0 * sc), f2bf(a1 * sc), f2bf(a2 * sc), f2bf(a3 * sc));
    *reinterpret_cast<ushort4*>(&out[(size_t)d * FEAT + t * 4]) = o;
}

// ---------------- f32-gather variant (fallback when ws is small) ----------------
__global__ void seg_mean_f32_kernel(const float* __restrict__ X, const int* __restrict__ off,
                                    const int* __restrict__ csr, ushort* __restrict__ out) {
    int d = blockIdx.x;
    int t = threadIdx.x;
    int beg = off[d], end = off[d + 1];
    float a0 = 0.f, a1 = 0.f, a2 = 0.f, a3 = 0.f;
    for (int j = beg; j < end; ++j) {
        int s = csr[j];
        float4 v = *reinterpret_cast<const float4*>(&X[(size_t)s * FEAT + t * 4]);
        a0 += v.x; a1 += v.y; a2 += v.z; a3 += v.w;
    }
    float sc = 1.0f / (float)max(end - beg, 1);
    ushort4 o = make_ushort4(f2bf(a0 * sc), f2bf(a1 * sc), f2bf(a2 * sc), f2bf(a3 * sc));
    *reinterpret_cast<ushort4*>(&out[(size_t)d * FEAT + t * 4]) = o;
}

// ---------------- bf16 MFMA GEMM: C = concat(A0,A1) @ BT^T + bias ----------------
template<int BM, int BN, int WGM, int WGN, bool RELU, bool OBF16>
__global__ __launch_bounds__(WGM * WGN * 64)
void gemm_mfma_kernel(const ushort* __restrict__ A0, const ushort* __restrict__ A1,
                      const ushort* __restrict__ BT, const float* __restrict__ bias,
                      ushort* __restrict__ Cb, float* __restrict__ Cf,
                      int M, int Nfull) {
    constexpr int NWAVE = WGM * WGN;
    constexpr int WM = BM / WGM;
    constexpr int WN = BN / WGN;
    constexpr int MF = WM / 16;
    constexpr int NF = WN / 16;
    constexpr int ACH = BM / 16;
    constexpr int BCH = BN / 16;

    __shared__ ushort Al[2][BM][32];
    __shared__ ushort Bl[2][BN][32];

    const int t = threadIdx.x;
    const int lane = t & 63;
    const int wid = t >> 6;
    const int wm = wid / WGN, wn = wid % WGN;
    const int lr = lane & 15, grp = lane >> 4;
    const int rowBase = blockIdx.y * BM;
    const int colBase = blockIdx.x * BN;

    f32x4 acc[MF][NF];
    #pragma unroll
    for (int m = 0; m < MF; ++m)
        #pragma unroll
        for (int n = 0; n < NF; ++n)
            acc[m][n] = (f32x4){0.f, 0.f, 0.f, 0.f};

    auto stage = [&](int buf, int kt) {
        const ushort* Asrc = (kt < 8) ? A0 : A1;
        const int kcol = (kt * 32) & 255;
        #pragma unroll
        for (int ch = wid; ch < ACH; ch += NWAVE) {
            int r = ch * 16 + (lane >> 2);
            int rg = min(rowBase + r, M - 1);
            int c = lane & 3;
            int ksw = (c ^ (r & 3)) * 8;
            gload_lds16(&Asrc[(size_t)rg * 256 + kcol + ksw], &Al[buf][ch * 16][0]);
        }
        #pragma unroll
        for (int ch = wid; ch < BCH; ch += NWAVE) {
            int r = ch * 16 + (lane >> 2);
            int c = lane & 3;
            int ksw = (c ^ (r & 3)) * 8;
            gload_lds16(&BT[(size_t)(colBase + r) * 512 + kt * 32 + ksw], &Bl[buf][ch * 16][0]);
        }
    };

    stage(0, 0);
    __syncthreads();

    int buf = 0;
    for (int kt = 0; kt < 16; ++kt) {
        if (kt + 1 < 16) stage(buf ^ 1, kt + 1);
        bf16x8 af[MF], bfr[NF];
        #pragma unroll
        for (int m = 0; m < MF; ++m) {
            int r = wm * WM + m * 16 + lr;
            af[m] = *reinterpret_cast<const bf16x8*>(
                (const char*)&Al[buf][0][0] + r * 64 + ((grp ^ (r & 3)) << 4));
        }
        #pragma unroll
        for (int n = 0; n < NF; ++n) {
            int r = wn * WN + n * 16 + lr;
            bfr[n] = *reinterpret_cast<const bf16x8*>(
                (const char*)&Bl[buf][0][0] + r * 64 + ((grp ^ (r & 3)) << 4));
        }
        #pragma unroll
        for (int m = 0; m < MF; ++m)
            #pragma unroll
            for (int n = 0; n < NF; ++n)
                acc[m][n] = __builtin_amdgcn_mfma_f32_16x16x32_bf16(af[m], bfr[n], acc[m][n], 0, 0, 0);
        __syncthreads();
        buf ^= 1;
    }

    #pragma unroll
    for (int m = 0; m < MF; ++m) {
        #pragma unroll
        for (int q = 0; q < 4; ++q) {
            int rowg = rowBase + wm * WM + m * 16 + grp * 4 + q;
            if (rowg >= M) continue;
            #pragma unroll
            for (int n = 0; n < NF; ++n) {
                int colg = colBase + wn * WN + n * 16 + lr;
                float v = acc[m][n][q] + bias[colg];
                if (RELU) v = fmaxf(v, 0.f);
                if (OBF16) Cb[(size_t)rowg * Nfull + colg] = f2bf(v);
                else       Cf[(size_t)rowg * Nfull + colg] = v;
            }
        }
    }
}

extern "C" void kernel_launch(void* const* d_in, const int* in_sizes, int n_in,
                              void* d_out, int out_size, void* d_ws, size_t ws_size,
                              hipStream_t stream) {
    const float* x  = (const float*)d_in[0];
    const float* W1 = (const float*)d_in[1];
    const float* b1 = (const float*)d_in[2];
    const float* W2 = (const float*)d_in[3];
    const float* b2 = (const float*)d_in[4];
    const int* src1 = (const int*)d_in[5];
    const int* dst1 = (const int*)d_in[6];
    const int* src2 = (const int*)d_in[7];
    const int* dst2 = (const int*)d_in[8];
    const int E1 = in_sizes[5];
    const int E2 = in_sizes[7];
    const int N_SRC1 = in_sizes[0] / FEAT;   // 200000
    float* out = (float*)d_out;

    char* ws = (char*)d_ws;
    size_t o = 0;
    auto carve = [&](size_t bytes) { char* p = ws + o; o = (o + bytes + 255) & ~(size_t)255; return p; };
    int*    deg1 = (int*)   carve((size_t)N_DST1 * 4);
    int*    off1 = (int*)   carve((size_t)(N_DST1 + 1) * 4);
    int*    pos1 = (int*)   carve((size_t)N_DST1 * 4);
    int*    csr1 = (int*)   carve((size_t)E1 * 4);
    ushort* hN1b = (ushort*)carve((size_t)N_DST1 * FEAT * 2);
    ushort* hb   = (ushort*)carve((size_t)N_DST1 * FEAT * 2);
    int*    deg2 = (int*)   carve((size_t)N_DST2 * 4);
    int*    off2 = (int*)   carve((size_t)(N_DST2 + 1) * 4);
    int*    pos2 = (int*)   carve((size_t)N_DST2 * 4);
    int*    csr2 = (int*)   carve((size_t)E2 * 4);
    ushort* hN2b = (ushort*)carve((size_t)N_DST2 * FEAT * 2);
    ushort* W1T  = (ushort*)carve((size_t)256 * 512 * 2);
    ushort* W2T  = (ushort*)carve((size_t)64 * 512 * 2);
    // bf16 copy of x: full (200000 rows) if workspace allows, else first 50000 rows
    size_t full_bytes = (size_t)N_SRC1 * FEAT * 2;
    bool full = (o + full_bytes) <= ws_size;
    ushort* xb = (ushort*)carve(full ? full_bytes : (size_t)N_DST1 * FEAT * 2);

    // ---- CSR build, layer 1 ----
    hipMemsetAsync(deg1, 0, (size_t)N_DST1 * 4, stream);
    count_deg_kernel<<<(E1 + 255) / 256, 256, 0, stream>>>(dst1, E1, deg1);
    excl_scan_kernel<<<1, 1024, 0, stream>>>(deg1, N_DST1, off1, pos1);
    scatter_csr_kernel<<<(E1 + 255) / 256, 256, 0, stream>>>(src1, dst1, E1, pos1, csr1);

    // ---- conversions ----
    {
        int n8 = (full ? N_SRC1 : N_DST1) * FEAT / 8;
        cvt_bf16_kernel<<<(n8 + 255) / 256, 256, 0, stream>>>(x, xb, n8);
    }
    cvt_wt_kernel<<<512, 256, 0, stream>>>(W1, W1T, 256);
    cvt_wt_kernel<<<512, 64, 0, stream>>>(W2, W2T, 64);

    // ---- layer 1 aggregate + GEMM ----
    if (full)
        seg_mean_bf16_kernel<<<N_DST1, 64, 0, stream>>>(xb, off1, csr1, hN1b);
    else
        seg_mean_f32_kernel<<<N_DST1, 64, 0, stream>>>(x, off1, csr1, hN1b);
    gemm_mfma_kernel<128, 128, 2, 2, true, true><<<dim3(256 / 128, (N_DST1 + 127) / 128), 256, 0, stream>>>(
        xb, hN1b, W1T, b1, hb, nullptr, N_DST1, 256);

    // ---- CSR build, layer 2 ----
    hipMemsetAsync(deg2, 0, (size_t)N_DST2 * 4, stream);
    count_deg_kernel<<<(E2 + 255) / 256, 256, 0, stream>>>(dst2, E2, deg2);
    excl_scan_kernel<<<1, 1024, 0, stream>>>(deg2, N_DST2, off2, pos2);
    scatter_csr_kernel<<<(E2 + 255) / 256, 256, 0, stream>>>(src2, dst2, E2, pos2, csr2);

    // ---- layer 2 aggregate + GEMM (f32 out) ----
    seg_mean_bf16_kernel<<<N_DST2, 64, 0, stream>>>(hb, off2, csr2, hN2b);
    gemm_mfma_kernel<128, 64, 2, 2, false, false><<<dim3(64 / 64, (N_DST2 + 127) / 128), 256, 0, stream>>>(
        hb, hN2b, W2T, b2, nullptr, out, N_DST2, 64);
}

// Round 4
// 337.235 us; speedup vs baseline: 1.9081x; 1.1952x over previous
//
#include <hip/hip_runtime.h>
#include <hip/hip_bf16.h>

#define N_DST1 50000
#define N_DST2 10000
#define FEAT   256

typedef unsigned int u32;
typedef __attribute__((ext_vector_type(4))) float f32x4;
typedef __attribute__((ext_vector_type(8))) short bf16x8;

__device__ __forceinline__ ushort f2bf(float f) {
    u32 u = __float_as_uint(f);
    u32 r = (u + 0x7FFFu + ((u >> 16) & 1u)) >> 16;
    return (ushort)r;
}
__device__ __forceinline__ float bf2f(ushort u) {
    return __uint_as_float(((u32)u) << 16);
}

__device__ __forceinline__ void gload_lds16(const void* g, void* l) {
    __builtin_amdgcn_global_load_lds(
        (const __attribute__((address_space(1))) u32*)g,
        (__attribute__((address_space(3))) u32*)l, 16, 0, 0);
}

// ---------------- merged degree count (both graphs) ----------------
__global__ void count_deg2_kernel(const int* __restrict__ dst1, int E1, int* __restrict__ deg1,
                                  const int* __restrict__ dst2, int E2, int* __restrict__ deg2) {
    int i = blockIdx.x * blockDim.x + threadIdx.x;
    if (i < E1) atomicAdd(&deg1[dst1[i]], 1);
    else {
        int k = i - E1;
        if (k < E2) atomicAdd(&deg2[dst2[k]], 1);
    }
}

// ---------------- merged scatter (both graphs) ----------------
__global__ void scatter_csr2_kernel(const int* __restrict__ src1, const int* __restrict__ dst1,
                                    int E1, int* __restrict__ pos1, int* __restrict__ csr1,
                                    const int* __restrict__ src2, const int* __restrict__ dst2,
                                    int E2, int* __restrict__ pos2, int* __restrict__ csr2) {
    int i = blockIdx.x * blockDim.x + threadIdx.x;
    if (i < E1) {
        int slot = atomicAdd(&pos1[dst1[i]], 1);
        csr1[slot] = src1[i];
    } else {
        int k = i - E1;
        if (k < E2) {
            int slot = atomicAdd(&pos2[dst2[k]], 1);
            csr2[slot] = src2[k];
        }
    }
}

// ---------------- dual exclusive scan: block 0 -> A, block 1 -> B (int4, n%4==0) ----------------
__global__ void excl_scan2_kernel(const int* __restrict__ degA, int nA, int* __restrict__ offA, int* __restrict__ posA,
                                  const int* __restrict__ degB, int nB, int* __restrict__ offB, int* __restrict__ posB) {
    const int* deg = (blockIdx.x == 0) ? degA : degB;
    int*       off = (blockIdx.x == 0) ? offA : offB;
    int*       pos = (blockIdx.x == 0) ? posA : posB;
    int n = (blockIdx.x == 0) ? nA : nB;
    int n4 = n >> 2;

    __shared__ int wsum[16];
    __shared__ int carry_s;
    int t = threadIdx.x;
    int lane = t & 63, wid = t >> 6;
    if (t == 0) carry_s = 0;
    __syncthreads();
    for (int base = 0; base < n4; base += 1024) {
        int i = base + t;
        int4 v = make_int4(0, 0, 0, 0);
        if (i < n4) v = reinterpret_cast<const int4*>(deg)[i];
        int tot = v.x + v.y + v.z + v.w;
        int s = tot;
        #pragma unroll
        for (int d = 1; d < 64; d <<= 1) {
            int u = __shfl_up(s, d, 64);
            if (lane >= d) s += u;
        }
        if (lane == 63) wsum[wid] = s;
        __syncthreads();
        if (wid == 0 && lane < 16) {
            int ws = wsum[lane];
            #pragma unroll
            for (int d = 1; d < 16; d <<= 1) {
                int u = __shfl_up(ws, d, 64);
                if (lane >= d) ws += u;
            }
            wsum[lane] = ws;
        }
        __syncthreads();
        int waveoff = (wid == 0) ? 0 : wsum[wid - 1];
        int carry = carry_s;
        int base0 = carry + waveoff + s - tot;
        if (i < n4) {
            int4 e;
            e.x = base0;
            e.y = base0 + v.x;
            e.z = base0 + v.x + v.y;
            e.w = base0 + v.x + v.y + v.z;
            reinterpret_cast<int4*>(off)[i] = e;
            reinterpret_cast<int4*>(pos)[i] = e;
        }
        __syncthreads();
        if (t == 0) carry_s = carry + wsum[15];
        __syncthreads();
    }
    if (t == 0) off[n] = carry_s;
}

// ---------------- f32 -> bf16 conversion (8 elems/thread) ----------------
__global__ void cvt_bf16_kernel(const float* __restrict__ in, ushort* __restrict__ out, int n8) {
    int i = blockIdx.x * blockDim.x + threadIdx.x;
    if (i >= n8) return;
    const float4* p = (const float4*)in + (size_t)i * 2;
    float4 a = p[0], b = p[1];
    ushort4 lo = make_ushort4(f2bf(a.x), f2bf(a.y), f2bf(a.z), f2bf(a.w));
    ushort4 hi = make_ushort4(f2bf(b.x), f2bf(b.y), f2bf(b.z), f2bf(b.w));
    ushort4* q = (ushort4*)out + (size_t)i * 2;
    q[0] = lo; q[1] = hi;
}

// ---------------- both W transposes: W[512][N] f32 -> WT[N][512] bf16 ----------------
__global__ void cvt_wt2_kernel(const float* __restrict__ W1, ushort* __restrict__ W1T,
                               const float* __restrict__ W2, ushort* __restrict__ W2T) {
    int k = blockIdx.x;          // 512 blocks
    int t = threadIdx.x;         // 320 threads
    if (t < 256) W1T[(size_t)t * 512 + k] = f2bf(W1[(size_t)k * 256 + t]);
    else {
        int n = t - 256;         // < 64
        W2T[(size_t)n * 512 + k] = f2bf(W2[(size_t)k * 64 + n]);
    }
}

// ---------------- segment mean (bf16 gather), 2 rows/wave, 16B/lane ----------------
__global__ void seg_mean_bf16_kernel(const ushort* __restrict__ X, const int* __restrict__ off,
                                     const int* __restrict__ csr, ushort* __restrict__ out) {
    int d = blockIdx.x;
    int l = threadIdx.x;              // 64 lanes
    int half = l >> 5;                // which row of the pair
    int f8 = (l & 31) * 8;            // feature base (8 features, 16B)
    int beg = off[d], end = off[d + 1];
    float acc[8] = {0.f, 0.f, 0.f, 0.f, 0.f, 0.f, 0.f, 0.f};
    int j = beg;
    for (; j + 8 <= end; j += 8) {
        #pragma unroll
        for (int p = 0; p < 4; ++p) {
            int r = csr[j + p * 2 + half];
            bf16x8 v = *reinterpret_cast<const bf16x8*>(&X[(size_t)r * FEAT + f8]);
            #pragma unroll
            for (int q = 0; q < 8; ++q) acc[q] += bf2f((ushort)v[q]);
        }
    }
    for (; j < end; j += 2) {
        int idx = j + half;
        float m = (idx < end) ? 1.f : 0.f;
        int r = csr[min(idx, end - 1)];
        bf16x8 v = *reinterpret_cast<const bf16x8*>(&X[(size_t)r * FEAT + f8]);
        #pragma unroll
        for (int q = 0; q < 8; ++q) acc[q] += m * bf2f((ushort)v[q]);
    }
    #pragma unroll
    for (int q = 0; q < 8; ++q) acc[q] += __shfl_xor(acc[q], 32);
    if (l < 32) {
        float sc = 1.0f / (float)max(end - beg, 1);
        bf16x8 ov;
        #pragma unroll
        for (int q = 0; q < 8; ++q) ov[q] = (short)f2bf(acc[q] * sc);
        *reinterpret_cast<bf16x8*>(&out[(size_t)d * FEAT + f8]) = ov;
    }
}

// ---------------- f32-gather fallback (small ws) ----------------
__global__ void seg_mean_f32_kernel(const float* __restrict__ X, const int* __restrict__ off,
                                    const int* __restrict__ csr, ushort* __restrict__ out) {
    int d = blockIdx.x;
    int t = threadIdx.x;
    int beg = off[d], end = off[d + 1];
    float a0 = 0.f, a1 = 0.f, a2 = 0.f, a3 = 0.f;
    for (int j = beg; j < end; ++j) {
        int s = csr[j];
        float4 v = *reinterpret_cast<const float4*>(&X[(size_t)s * FEAT + t * 4]);
        a0 += v.x; a1 += v.y; a2 += v.z; a3 += v.w;
    }
    float sc = 1.0f / (float)max(end - beg, 1);
    ushort4 o = make_ushort4(f2bf(a0 * sc), f2bf(a1 * sc), f2bf(a2 * sc), f2bf(a3 * sc));
    *reinterpret_cast<ushort4*>(&out[(size_t)d * FEAT + t * 4]) = o;
}

// ---------------- bf16 MFMA GEMM: C = concat(A0,A1) @ BT^T + bias ----------------
template<int BM, int BN, int WGM, int WGN, bool RELU, bool OBF16>
__global__ __launch_bounds__(WGM * WGN * 64)
void gemm_mfma_kernel(const ushort* __restrict__ A0, const ushort* __restrict__ A1,
                      const ushort* __restrict__ BT, const float* __restrict__ bias,
                      ushort* __restrict__ Cb, float* __restrict__ Cf,
                      int M, int Nfull) {
    constexpr int NWAVE = WGM * WGN;
    constexpr int WM = BM / WGM;
    constexpr int WN = BN / WGN;
    constexpr int MF = WM / 16;
    constexpr int NF = WN / 16;
    constexpr int ACH = BM / 16;
    constexpr int BCH = BN / 16;

    __shared__ ushort Al[2][BM][32];
    __shared__ ushort Bl[2][BN][32];

    const int t = threadIdx.x;
    const int lane = t & 63;
    const int wid = t >> 6;
    const int wm = wid / WGN, wn = wid % WGN;
    const int lr = lane & 15, grp = lane >> 4;
    const int rowBase = blockIdx.y * BM;
    const int colBase = blockIdx.x * BN;

    f32x4 acc[MF][NF];
    #pragma unroll
    for (int m = 0; m < MF; ++m)
        #pragma unroll
        for (int n = 0; n < NF; ++n)
            acc[m][n] = (f32x4){0.f, 0.f, 0.f, 0.f};

    auto stage = [&](int buf, int kt) {
        const ushort* Asrc = (kt < 8) ? A0 : A1;
        const int kcol = (kt * 32) & 255;
        #pragma unroll
        for (int ch = wid; ch < ACH; ch += NWAVE) {
            int r = ch * 16 + (lane >> 2);
            int rg = min(rowBase + r, M - 1);
            int c = lane & 3;
            int ksw = (c ^ (r & 3)) * 8;
            gload_lds16(&Asrc[(size_t)rg * 256 + kcol + ksw], &Al[buf][ch * 16][0]);
        }
        #pragma unroll
        for (int ch = wid; ch < BCH; ch += NWAVE) {
            int r = ch * 16 + (lane >> 2);
            int c = lane & 3;
            int ksw = (c ^ (r & 3)) * 8;
            gload_lds16(&BT[(size_t)(colBase + r) * 512 + kt * 32 + ksw], &Bl[buf][ch * 16][0]);
        }
    };

    stage(0, 0);
    __syncthreads();

    int buf = 0;
    for (int kt = 0; kt < 16; ++kt) {
        if (kt + 1 < 16) stage(buf ^ 1, kt + 1);
        bf16x8 af[MF], bfr[NF];
        #pragma unroll
        for (int m = 0; m < MF; ++m) {
            int r = wm * WM + m * 16 + lr;
            af[m] = *reinterpret_cast<const bf16x8*>(
                (const char*)&Al[buf][0][0] + r * 64 + ((grp ^ (r & 3)) << 4));
        }
        #pragma unroll
        for (int n = 0; n < NF; ++n) {
            int r = wn * WN + n * 16 + lr;
            bfr[n] = *reinterpret_cast<const bf16x8*>(
                (const char*)&Bl[buf][0][0] + r * 64 + ((grp ^ (r & 3)) << 4));
        }
        #pragma unroll
        for (int m = 0; m < MF; ++m)
            #pragma unroll
            for (int n = 0; n < NF; ++n)
                acc[m][n] = __builtin_amdgcn_mfma_f32_16x16x32_bf16(af[m], bfr[n], acc[m][n], 0, 0, 0);
        __syncthreads();
        buf ^= 1;
    }

    #pragma unroll
    for (int m = 0; m < MF; ++m) {
        #pragma unroll
        for (int q = 0; q < 4; ++q) {
            int rowg = rowBase + wm * WM + m * 16 + grp * 4 + q;
            if (rowg >= M) continue;
            #pragma unroll
            for (int n = 0; n < NF; ++n) {
                int colg = colBase + wn * WN + n * 16 + lr;
                float v = acc[m][n][q] + bias[colg];
                if (RELU) v = fmaxf(v, 0.f);
                if (OBF16) Cb[(size_t)rowg * Nfull + colg] = f2bf(v);
                else       Cf[(size_t)rowg * Nfull + colg] = v;
            }
        }
    }
}

extern "C" void kernel_launch(void* const* d_in, const int* in_sizes, int n_in,
                              void* d_out, int out_size, void* d_ws, size_t ws_size,
                              hipStream_t stream) {
    const float* x  = (const float*)d_in[0];
    const float* W1 = (const float*)d_in[1];
    const float* b1 = (const float*)d_in[2];
    const float* W2 = (const float*)d_in[3];
    const float* b2 = (const float*)d_in[4];
    const int* src1 = (const int*)d_in[5];
    const int* dst1 = (const int*)d_in[6];
    const int* src2 = (const int*)d_in[7];
    const int* dst2 = (const int*)d_in[8];
    const int E1 = in_sizes[5];
    const int E2 = in_sizes[7];
    const int N_SRC1 = in_sizes[0] / FEAT;   // 200000
    float* out = (float*)d_out;

    char* ws = (char*)d_ws;
    size_t o = 0;
    auto carve = [&](size_t bytes) { char* p = ws + o; o = (o + bytes + 255) & ~(size_t)255; return p; };
    int*    degs = (int*)   carve((size_t)(N_DST1 + N_DST2) * 4);   // deg1 | deg2 contiguous
    int*    deg1 = degs;
    int*    deg2 = degs + N_DST1;
    int*    off1 = (int*)   carve((size_t)(N_DST1 + 1) * 4);
    int*    pos1 = (int*)   carve((size_t)N_DST1 * 4);
    int*    csr1 = (int*)   carve((size_t)E1 * 4);
    ushort* hN1b = (ushort*)carve((size_t)N_DST1 * FEAT * 2);
    ushort* hb   = (ushort*)carve((size_t)N_DST1 * FEAT * 2);
    int*    off2 = (int*)   carve((size_t)(N_DST2 + 1) * 4);
    int*    pos2 = (int*)   carve((size_t)N_DST2 * 4);
    int*    csr2 = (int*)   carve((size_t)E2 * 4);
    ushort* hN2b = (ushort*)carve((size_t)N_DST2 * FEAT * 2);
    ushort* W1T  = (ushort*)carve((size_t)256 * 512 * 2);
    ushort* W2T  = (ushort*)carve((size_t)64 * 512 * 2);
    size_t full_bytes = (size_t)N_SRC1 * FEAT * 2;
    bool full = (o + full_bytes) <= ws_size;
    ushort* xb = (ushort*)carve(full ? full_bytes : (size_t)N_DST1 * FEAT * 2);

    // ---- CSR build (both graphs) ----
    hipMemsetAsync(degs, 0, (size_t)(N_DST1 + N_DST2) * 4, stream);
    {
        int tot = E1 + E2;
        count_deg2_kernel<<<(tot + 255) / 256, 256, 0, stream>>>(dst1, E1, deg1, dst2, E2, deg2);
        excl_scan2_kernel<<<2, 1024, 0, stream>>>(deg1, N_DST1, off1, pos1, deg2, N_DST2, off2, pos2);
        scatter_csr2_kernel<<<(tot + 255) / 256, 256, 0, stream>>>(
            src1, dst1, E1, pos1, csr1, src2, dst2, E2, pos2, csr2);
    }

    // ---- conversions ----
    {
        int n8 = (full ? N_SRC1 : N_DST1) * FEAT / 8;
        cvt_bf16_kernel<<<(n8 + 255) / 256, 256, 0, stream>>>(x, xb, n8);
    }
    cvt_wt2_kernel<<<512, 320, 0, stream>>>(W1, W1T, W2, W2T);

    // ---- layer 1: aggregate + GEMM (BN=256, A read once) ----
    if (full)
        seg_mean_bf16_kernel<<<N_DST1, 64, 0, stream>>>(xb, off1, csr1, hN1b);
    else
        seg_mean_f32_kernel<<<N_DST1, 64, 0, stream>>>(x, off1, csr1, hN1b);
    gemm_mfma_kernel<128, 256, 2, 4, true, true><<<dim3(1, (N_DST1 + 127) / 128), 512, 0, stream>>>(
        xb, hN1b, W1T, b1, hb, nullptr, N_DST1, 256);

    // ---- layer 2: aggregate + GEMM (f32 out) ----
    seg_mean_bf16_kernel<<<N_DST2, 64, 0, stream>>>(hb, off2, csr2, hN2b);
    gemm_mfma_kernel<64, 64, 2, 2, false, false><<<dim3(1, (N_DST2 + 63) / 64), 256, 0, stream>>>(
        hb, hN2b, W2T, b2, nullptr, out, N_DST2, 64);
}